// Round 4
// baseline (206.573 us; speedup 1.0000x reference)
//
#include <hip/hip_runtime.h>
#include <hip/hip_bf16.h>

// Causal attention, B=2 NH=16 T=2048 D=64, fp32 I/O.
// R4: split-K flash (max-free softmax => partials combine by pure addition).
// 1280 uniform-ish blocks (chunks of <=8 k-tiles), 32 KB LDS single-buffered
// K/V => 5 blocks/CU all-resident (20 waves/CU) for latency hiding.
// Chunk table arranged so each CU's 5 round-robin blocks sum to 34 iters.
// Blocks atomic-add O^T numerators + l into ws; norm kernel transposes/divides.

typedef __bf16 bf16;
typedef __bf16 bf16x4 __attribute__((ext_vector_type(4)));
typedef __bf16 bf16x8 __attribute__((ext_vector_type(8)));
typedef float floatx4 __attribute__((ext_vector_type(4)));

#define T_SEQ 2048
#define DH 64
#define TQ 128
#define TK 64
#define BHN 32
#define CEXP 0.18033688011112042f  // (1/sqrt(64)) * log2(e)

__device__ __forceinline__ void gload16(const bf16* g, bf16* l) {
    __builtin_amdgcn_global_load_lds(
        (const __attribute__((address_space(1))) void*)g,
        (__attribute__((address_space(3))) void*)l, 16, 0, 0);
}

// 40 chunks per bh: (iq, first k-tile, #k-tiles). Ordered so residue classes
// mod 8 of r each sum to 34 iters (5 blocks/CU round-robin => perfect balance).
__device__ __constant__ unsigned char iq_tab[40] = {
    15,15,15,15, 14,14,14, 13,13,13, 12,12,12, 11,11,11,
    10,10, 9,9, 8,8, 7,7, 6,5,4,3,
    14,10,6,2, 12,8,4,0, 13,9,5,1};
__device__ __constant__ unsigned char k0_tab[40] = {
    0,8,16,24, 0,8,16, 0,8,16, 0,8,16, 0,8,16,
    0,8, 0,8, 0,8, 0,8, 0,0,0,0,
    24,16,8,0, 24,16,8,0, 24,16,8,0};
__device__ __constant__ unsigned char len_tab[40] = {
    8,8,8,8,8,8,8,8,8,8,8,8,8,8,8,8,8,8,8,8,8,8,8,8,8,8,8,8,
    6,6,6,6, 2,2,2,2, 4,4,4,4};

// ---------------- fused prepass ----------------
// bid [0,1024): K fp32 -> bf16 flat. bid [1024,2048): V -> V^T bf16.
// bid [2048,3088): zero the On/Ls accumulator region (16.25 MiB).
__global__ __launch_bounds__(256) void prep(const float* __restrict__ K,
                                            const float* __restrict__ V,
                                            bf16* __restrict__ Kb,
                                            bf16* __restrict__ Vt,
                                            float* __restrict__ Zb) {
    const int bid = (int)blockIdx.x;
    const int tid = (int)threadIdx.x;
    if (bid >= 2048) {                     // zero On + Ls
        const size_t idx = ((size_t)(bid - 2048) * 1024 + tid * 4) * 4;
        float4 z = {0.f, 0.f, 0.f, 0.f};
        *(float4*)(Zb + idx + 0)  = z;
        *(float4*)(Zb + idx + 4)  = z;
        *(float4*)(Zb + idx + 8)  = z;
        *(float4*)(Zb + idx + 12) = z;
        return;
    }
    if (bid < 1024) {                      // K convert
        const size_t i = ((size_t)bid * 256 + tid) * 16;
        float4 a = *(const float4*)(K + i + 0);
        float4 b = *(const float4*)(K + i + 4);
        float4 c = *(const float4*)(K + i + 8);
        float4 d = *(const float4*)(K + i + 12);
        bf16x8 o0, o1;
        o0[0]=(bf16)a.x; o0[1]=(bf16)a.y; o0[2]=(bf16)a.z; o0[3]=(bf16)a.w;
        o0[4]=(bf16)b.x; o0[5]=(bf16)b.y; o0[6]=(bf16)b.z; o0[7]=(bf16)b.w;
        o1[0]=(bf16)c.x; o1[1]=(bf16)c.y; o1[2]=(bf16)c.z; o1[3]=(bf16)c.w;
        o1[4]=(bf16)d.x; o1[5]=(bf16)d.y; o1[6]=(bf16)d.z; o1[7]=(bf16)d.w;
        *(bf16x8*)(Kb + i + 0) = o0;
        *(bf16x8*)(Kb + i + 8) = o1;
        return;
    }
    // V transpose
    __shared__ bf16 tile[64][72];
    const int vb = bid - 1024;
    const int bh = vb & (BHN - 1);
    const int t0 = (vb >> 5) * 64;
    {
        const int r = tid >> 2;
        const int c = (tid & 3) * 16;
        const float* s = V + ((size_t)bh * T_SEQ + t0 + r) * DH + c;
        float4 f0 = *(const float4*)(s + 0);
        float4 f1 = *(const float4*)(s + 4);
        float4 f2 = *(const float4*)(s + 8);
        float4 f3 = *(const float4*)(s + 12);
        bf16x8 p0, p1;
        p0[0]=(bf16)f0.x; p0[1]=(bf16)f0.y; p0[2]=(bf16)f0.z; p0[3]=(bf16)f0.w;
        p0[4]=(bf16)f1.x; p0[5]=(bf16)f1.y; p0[6]=(bf16)f1.z; p0[7]=(bf16)f1.w;
        p1[0]=(bf16)f2.x; p1[1]=(bf16)f2.y; p1[2]=(bf16)f2.z; p1[3]=(bf16)f2.w;
        p1[4]=(bf16)f3.x; p1[5]=(bf16)f3.y; p1[6]=(bf16)f3.z; p1[7]=(bf16)f3.w;
        *(bf16x8*)&tile[r][c + 0] = p0;
        *(bf16x8*)&tile[r][c + 8] = p1;
    }
    __syncthreads();
    {
        const int d   = tid >> 2;
        const int tch = (tid & 3) * 16;
        bf16x8 o0, o1;
        #pragma unroll
        for (int j = 0; j < 8; ++j) { o0[j] = tile[tch + j][d]; o1[j] = tile[tch + 8 + j][d]; }
        bf16* o = Vt + ((size_t)bh * DH + d) * T_SEQ + t0 + tch;
        *(bf16x8*)(o + 0) = o0;
        *(bf16x8*)(o + 8) = o1;
    }
}

// ---------------- main flash kernel (S^T, split-K chunks) ----------------
// S^T = K·Q^T (A=K from LDS, B=Q regs); O^T += V^T·P^T (A=V^T LDS, B=P^T LDS).
// LDS rows = 8 x 16B chunks, slot chunk i of row r holds global chunk i^(r&7).
__global__ __launch_bounds__(256, 5)
void fa_fwd(const float* __restrict__ Qg, const bf16* __restrict__ Kb,
            const bf16* __restrict__ Vt, float* __restrict__ On,
            float* __restrict__ Ls)
{
    __shared__ __align__(16) bf16 Ksh[TK * DH];     // 8 KB [key][dim]
    __shared__ __align__(16) bf16 Vsh[DH * TK];     // 8 KB [dim][key]
    __shared__ __align__(16) bf16 Psh[4][32 * TK];  // 4 KB/wave [q][key]

    const int gid = (int)blockIdx.x;
    const int r_  = gid >> 5;
    const int bh  = gid & (BHN - 1);
    const int iq  = iq_tab[r_];
    const int kt0 = k0_tab[r_];
    const int nk  = len_tab[r_];
    const int q0  = iq * TQ;

    const int tid  = (int)threadIdx.x;
    const int wave = tid >> 6;
    const int lane = tid & 63;
    const int quad = lane >> 4;
    const int l16  = lane & 15;
    const int rl   = lane >> 3;
    const int gch  = (lane & 7) ^ rl;

    const bf16* Kbh = Kb + (size_t)bh * T_SEQ * DH;
    const bf16* Vbh = Vt + (size_t)bh * DH * T_SEQ;
    const int qw = q0 + wave * 32;

    // Q as B-fragments (registers): B[k=quad*8+j][n=l16]
    bf16x8 qb[2][2];
    #pragma unroll
    for (int nt = 0; nt < 2; ++nt) {
        const int qrow = qw + nt * 16 + l16;
        #pragma unroll
        for (int kk = 0; kk < 2; ++kk) {
            const float* s = Qg + ((size_t)bh * T_SEQ + qrow) * DH + kk * 32 + quad * 8;
            float4 f0 = *(const float4*)(s);
            float4 f1 = *(const float4*)(s + 4);
            bf16x8 t;
            t[0]=(bf16)f0.x; t[1]=(bf16)f0.y; t[2]=(bf16)f0.z; t[3]=(bf16)f0.w;
            t[4]=(bf16)f1.x; t[5]=(bf16)f1.y; t[6]=(bf16)f1.z; t[7]=(bf16)f1.w;
            qb[nt][kk] = t;
        }
    }

    floatx4 oacc[4][2];
    #pragma unroll
    for (int mt = 0; mt < 4; ++mt)
        #pragma unroll
        for (int nt = 0; nt < 2; ++nt) oacc[mt][nt] = (floatx4){0.f,0.f,0.f,0.f};
    float lpart[2] = {0.f, 0.f};

    for (int it = 0; it < nk; ++it) {
        const int kt = kt0 + it;
        const int k0 = kt * TK;
        {   // stage K tile + V^T tile (4 DMA instrs/lane)
            const bf16* kg = Kbh + (size_t)kt * TK * DH;
            const bf16* vg = Vbh + kt * TK;
            #pragma unroll
            for (int g = 0; g < 2; ++g) {
                const int row = wave * 16 + g * 8;
                gload16(kg + (size_t)(row + rl) * DH + gch * 8, &Ksh[row * DH]);
                gload16(vg + (size_t)(row + rl) * T_SEQ + gch * 8, &Vsh[row * TK]);
            }
        }
        __syncthreads();   // vmcnt drained; tiles visible

        // ---- S^T = K · Q^T ----
        floatx4 sacc[4][2];
        #pragma unroll
        for (int mt = 0; mt < 4; ++mt)
            #pragma unroll
            for (int nt = 0; nt < 2; ++nt) sacc[mt][nt] = (floatx4){0.f,0.f,0.f,0.f};
        #pragma unroll
        for (int kk = 0; kk < 2; ++kk) {
            #pragma unroll
            for (int mt = 0; mt < 4; ++mt) {
                const int R = mt * 16 + l16;
                bf16x8 kf = *(const bf16x8*)&Ksh[R * DH + (((kk * 4 + quad) ^ (l16 & 7)) * 8)];
                #pragma unroll
                for (int nt = 0; nt < 2; ++nt)
                    sacc[mt][nt] = __builtin_amdgcn_mfma_f32_16x16x32_bf16(kf, qb[nt][kk], sacc[mt][nt], 0, 0, 0);
            }
        }

        // ---- causal mask near diagonal ----
        if (k0 + TK - 1 > qw) {
            #pragma unroll
            for (int mt = 0; mt < 4; ++mt) {
                #pragma unroll
                for (int nt = 0; nt < 2; ++nt) {
                    const int qg = qw + nt * 16 + l16;
                    #pragma unroll
                    for (int r = 0; r < 4; ++r) {
                        const int keyg = k0 + mt * 16 + quad * 4 + r;
                        if (keyg > qg) sacc[mt][nt][r] = -INFINITY;
                    }
                }
            }
        }

        // ---- p = exp2(cexp*s); P^T packed b64 -> LDS ----
        bf16* Pw = Psh[wave];
        #pragma unroll
        for (int mt = 0; mt < 4; ++mt) {
            #pragma unroll
            for (int nt = 0; nt < 2; ++nt) {
                bf16x4 w;
                #pragma unroll
                for (int r = 0; r < 4; ++r) {
                    const float p = __builtin_amdgcn_exp2f(CEXP * sacc[mt][nt][r]);
                    lpart[nt] += p;
                    w[r] = (bf16)p;
                }
                const int row = nt * 16 + l16;
                const int c   = (mt * 2 + (quad >> 1)) ^ (row & 7);
                *(bf16x4*)&Pw[row * TK + c * 8 + (quad & 1) * 4] = w;
            }
        }

        // ---- P^T B-fragments ----
        bf16x8 pf[2][2];
        #pragma unroll
        for (int nt = 0; nt < 2; ++nt) {
            const int row = nt * 16 + l16;
            #pragma unroll
            for (int kk = 0; kk < 2; ++kk)
                pf[nt][kk] = *(const bf16x8*)&Pw[row * TK + (((kk * 4 + quad) ^ (row & 7)) * 8)];
        }

        // ---- O^T += V^T · P^T ----
        #pragma unroll
        for (int kk = 0; kk < 2; ++kk) {
            #pragma unroll
            for (int mt = 0; mt < 4; ++mt) {
                const int R = mt * 16 + l16;
                bf16x8 vf = *(const bf16x8*)&Vsh[R * TK + (((kk * 4 + quad) ^ (l16 & 7)) * 8)];
                #pragma unroll
                for (int nt = 0; nt < 2; ++nt)
                    oacc[mt][nt] = __builtin_amdgcn_mfma_f32_16x16x32_bf16(vf, pf[nt][kk], oacc[mt][nt], 0, 0, 0);
            }
        }

        __syncthreads();   // all waves done reading before next stage overwrites
    }

    // ---- epilogue: atomic-accumulate partials ----
    #pragma unroll
    for (int nt = 0; nt < 2; ++nt) {
        float v = lpart[nt];
        v += __shfl_xor(v, 16);
        v += __shfl_xor(v, 32);
        const int qglob = qw + nt * 16 + l16;
        if (quad == 0) atomicAdd(&Ls[(size_t)bh * T_SEQ + qglob], v);
        #pragma unroll
        for (int mt = 0; mt < 4; ++mt) {
            #pragma unroll
            for (int r = 0; r < 4; ++r) {
                const int d = mt * 16 + quad * 4 + r;
                atomicAdd(&On[((size_t)bh * DH + d) * T_SEQ + qglob], oacc[mt][nt][r]);
            }
        }
    }
}

// ---------------- normalize + transpose: O[q][d] = On^T[d][q] / Ls[q] ----------------
__global__ __launch_bounds__(256) void norm(const float* __restrict__ On,
                                            const float* __restrict__ Ls,
                                            float* __restrict__ O) {
    __shared__ float tile[64][65];   // stride 65: transposed reads 2-way (free)
    const int bh = (int)blockIdx.x & (BHN - 1);
    const int t0 = ((int)blockIdx.x >> 5) * 64;
    const int tid = (int)threadIdx.x;
    {
        const int r = tid >> 2;                 // d
        const int c = (tid & 3) * 16;           // q chunk
        const float* s = On + ((size_t)bh * DH + r) * T_SEQ + t0 + c;
        #pragma unroll
        for (int g = 0; g < 4; ++g) {
            float4 f = *(const float4*)(s + g * 4);
            tile[r][c + g * 4 + 0] = f.x;
            tile[r][c + g * 4 + 1] = f.y;
            tile[r][c + g * 4 + 2] = f.z;
            tile[r][c + g * 4 + 3] = f.w;
        }
    }
    __syncthreads();
    {
        const int q  = tid >> 2;
        const int dc = (tid & 3) * 16;
        const float linv = 1.0f / Ls[(size_t)bh * T_SEQ + t0 + q];
        float* dst = O + ((size_t)bh * T_SEQ + t0 + q) * DH + dc;
        #pragma unroll
        for (int g = 0; g < 4; ++g) {
            float4 o;
            o.x = tile[dc + g * 4 + 0][q] * linv;
            o.y = tile[dc + g * 4 + 1][q] * linv;
            o.z = tile[dc + g * 4 + 2][q] * linv;
            o.w = tile[dc + g * 4 + 3][q] * linv;
            *(float4*)(dst + g * 4) = o;
        }
    }
}

extern "C" void kernel_launch(void* const* d_in, const int* in_sizes, int n_in,
                              void* d_out, int out_size, void* d_ws, size_t ws_size,
                              hipStream_t stream) {
    const float* Q = (const float*)d_in[0];
    const float* K = (const float*)d_in[1];
    const float* V = (const float*)d_in[2];
    float* O = (float*)d_out;
    (void)in_sizes; (void)n_in; (void)out_size; (void)ws_size;

    const size_t nelem = (size_t)BHN * T_SEQ * DH;   // 4,194,304
    bf16*  Kbf = (bf16*)d_ws;            // 8 MiB
    bf16*  Vtb = Kbf + nelem;            // 8 MiB
    float* On  = (float*)(Vtb + nelem);  // 16 MiB (O^T numerators)
    float* Ls  = On + nelem;             // 256 KiB (denominators)
    // zero region = On..end of Ls = 16.25 MiB = 1040 blocks * 16 KiB

    prep<<<dim3(3088), dim3(256), 0, stream>>>(K, V, Kbf, Vtb, On);
    fa_fwd<<<dim3(1280), dim3(256), 0, stream>>>(Q, Kbf, Vtb, On, Ls);
    norm<<<dim3(1024), dim3(256), 0, stream>>>(On, Ls, O);
}

// Round 5
// 126.550 us; speedup vs baseline: 1.6323x; 1.6323x over previous
//
#include <hip/hip_runtime.h>
#include <hip/hip_bf16.h>

// Causal attention, B=2 NH=16 T=2048 D=64, fp32 I/O.
// R5: S^T flash, TQ=128, 512-thread blocks = two 4-wave k-groups (even/odd
// k-tiles) over the same q-tile; combine partials through LDS at the end
// (NO global atomics — R4's 197MB write-through disaster reverted).
// 64 KB LDS -> 2 blocks/CU = 16 waves/CU. Heavy/light q-tile pairing
// (gid, gid+256 co-resident) => uniform 17 supersteps per CU.

typedef __bf16 bf16;
typedef __bf16 bf16x4 __attribute__((ext_vector_type(4)));
typedef __bf16 bf16x8 __attribute__((ext_vector_type(8)));
typedef float floatx4 __attribute__((ext_vector_type(4)));

#define T_SEQ 2048
#define DH 64
#define TQ 128
#define TK 64
#define NQT (T_SEQ / TQ)   // 16
#define BHN 32
#define CEXP 0.18033688011112042f  // (1/sqrt(64)) * log2(e)

__device__ __forceinline__ void gload16(const bf16* g, bf16* l) {
    __builtin_amdgcn_global_load_lds(
        (const __attribute__((address_space(1))) void*)g,
        (__attribute__((address_space(3))) void*)l, 16, 0, 0);
}

// ---------------- fused prepass ----------------
// bid [0,1024): K fp32 -> bf16 flat. bid [1024,2048): V -> V^T bf16 (coalesced).
__global__ __launch_bounds__(256) void prep(const float* __restrict__ K,
                                            const float* __restrict__ V,
                                            bf16* __restrict__ Kb,
                                            bf16* __restrict__ Vt) {
    const int bid = (int)blockIdx.x;
    const int tid = (int)threadIdx.x;
    if (bid < 1024) {
        const size_t i = ((size_t)bid * 256 + tid) * 16;
        float4 a = *(const float4*)(K + i + 0);
        float4 b = *(const float4*)(K + i + 4);
        float4 c = *(const float4*)(K + i + 8);
        float4 d = *(const float4*)(K + i + 12);
        bf16x8 o0, o1;
        o0[0]=(bf16)a.x; o0[1]=(bf16)a.y; o0[2]=(bf16)a.z; o0[3]=(bf16)a.w;
        o0[4]=(bf16)b.x; o0[5]=(bf16)b.y; o0[6]=(bf16)b.z; o0[7]=(bf16)b.w;
        o1[0]=(bf16)c.x; o1[1]=(bf16)c.y; o1[2]=(bf16)c.z; o1[3]=(bf16)c.w;
        o1[4]=(bf16)d.x; o1[5]=(bf16)d.y; o1[6]=(bf16)d.z; o1[7]=(bf16)d.w;
        *(bf16x8*)(Kb + i + 0) = o0;
        *(bf16x8*)(Kb + i + 8) = o1;
        return;
    }
    __shared__ bf16 tile[64][72];
    const int vb = bid - 1024;
    const int bh = vb & (BHN - 1);
    const int t0 = (vb >> 5) * 64;
    {
        const int r = tid >> 2;
        const int c = (tid & 3) * 16;
        const float* s = V + ((size_t)bh * T_SEQ + t0 + r) * DH + c;
        float4 f0 = *(const float4*)(s + 0);
        float4 f1 = *(const float4*)(s + 4);
        float4 f2 = *(const float4*)(s + 8);
        float4 f3 = *(const float4*)(s + 12);
        bf16x8 p0, p1;
        p0[0]=(bf16)f0.x; p0[1]=(bf16)f0.y; p0[2]=(bf16)f0.z; p0[3]=(bf16)f0.w;
        p0[4]=(bf16)f1.x; p0[5]=(bf16)f1.y; p0[6]=(bf16)f1.z; p0[7]=(bf16)f1.w;
        p1[0]=(bf16)f2.x; p1[1]=(bf16)f2.y; p1[2]=(bf16)f2.z; p1[3]=(bf16)f2.w;
        p1[4]=(bf16)f3.x; p1[5]=(bf16)f3.y; p1[6]=(bf16)f3.z; p1[7]=(bf16)f3.w;
        *(bf16x8*)&tile[r][c + 0] = p0;
        *(bf16x8*)&tile[r][c + 8] = p1;
    }
    __syncthreads();
    {
        const int d   = tid >> 2;
        const int tch = (tid & 3) * 16;
        bf16x8 o0, o1;
        #pragma unroll
        for (int j = 0; j < 8; ++j) { o0[j] = tile[tch + j][d]; o1[j] = tile[tch + 8 + j][d]; }
        bf16* o = Vt + ((size_t)bh * DH + d) * T_SEQ + t0 + tch;
        *(bf16x8*)(o + 0) = o0;
        *(bf16x8*)(o + 8) = o1;
    }
}

// ---------------- main flash kernel ----------------
// LDS map (bf16 units): K[g] @ g*4096 (8KB ea), V[g] @ 8192+g*4096,
// P[w] @ 16384 + w*2048 (4KB/wave).  Total 64 KB.
// Combine reuses bytes [0,32768) as float scratch (8KB per wave-pair).
__global__ __launch_bounds__(512, 4)
void fa_fwd(const float* __restrict__ Qg, const bf16* __restrict__ Kb,
            const bf16* __restrict__ Vt, float* __restrict__ Og)
{
    __shared__ __align__(16) bf16 smem[32768];

    const int gid  = (int)blockIdx.x;
    const int half = gid >> 8;
    const int idx  = gid & 255;
    const int bh   = idx & (BHN - 1);
    const int p_   = idx >> 5;                 // 0..7
    const int iq   = half ? p_ : (NQT - 1 - p_);
    const int q0   = iq * TQ;
    const int nsteps = iq + 1;

    const int tid  = (int)threadIdx.x;
    const int wave = tid >> 6;
    const int w4   = wave & 3;                 // wave within group
    const int g2   = wave >> 2;                // k-group 0/1
    const int lane = tid & 63;
    const int quad = lane >> 4;
    const int l16  = lane & 15;
    const int rl   = lane >> 3;
    const int gch  = (lane & 7) ^ rl;

    bf16* Ksh = smem + g2 * 4096;
    bf16* Vsh = smem + 8192 + g2 * 4096;
    bf16* Pw  = smem + 16384 + wave * 2048;

    const bf16* Kbh = Kb + (size_t)bh * T_SEQ * DH;
    const bf16* Vbh = Vt + (size_t)bh * DH * T_SEQ;
    const int qw = q0 + w4 * 32;               // this wave's 32 q columns

    // Q as B-fragments: B[k=quad*8+j][n=l16]
    bf16x8 qb[2][2];
    #pragma unroll
    for (int nt = 0; nt < 2; ++nt) {
        const int qrow = qw + nt * 16 + l16;
        #pragma unroll
        for (int kk = 0; kk < 2; ++kk) {
            const float* s = Qg + ((size_t)bh * T_SEQ + qrow) * DH + kk * 32 + quad * 8;
            float4 f0 = *(const float4*)(s);
            float4 f1 = *(const float4*)(s + 4);
            bf16x8 t;
            t[0]=(bf16)f0.x; t[1]=(bf16)f0.y; t[2]=(bf16)f0.z; t[3]=(bf16)f0.w;
            t[4]=(bf16)f1.x; t[5]=(bf16)f1.y; t[6]=(bf16)f1.z; t[7]=(bf16)f1.w;
            qb[nt][kk] = t;
        }
    }

    floatx4 oacc[4][2];
    #pragma unroll
    for (int mt = 0; mt < 4; ++mt)
        #pragma unroll
        for (int nt = 0; nt < 2; ++nt) oacc[mt][nt] = (floatx4){0.f,0.f,0.f,0.f};
    float lpart[2] = {0.f, 0.f};

    for (int s = 0; s < nsteps; ++s) {
        const int kt = 2 * s + g2;
        const int k0 = kt * TK;
        {   // stage this group's K tile + V^T tile (4 DMA instrs/lane)
            const bf16* kg = Kbh + (size_t)kt * TK * DH;
            const bf16* vg = Vbh + kt * TK;
            #pragma unroll
            for (int g = 0; g < 2; ++g) {
                const int row = w4 * 16 + g * 8;
                gload16(kg + (size_t)(row + rl) * DH + gch * 8, &Ksh[row * DH]);
                gload16(vg + (size_t)(row + rl) * T_SEQ + gch * 8, &Vsh[row * TK]);
            }
        }
        __syncthreads();   // DMA drained, tiles visible

        const bool domask = (k0 + TK - 1 > qw);

        // ---- per-mt: S^T block, mask, exp, P^T -> LDS (keeps sacc live range small) ----
        #pragma unroll
        for (int mt = 0; mt < 4; ++mt) {
            floatx4 s0 = (floatx4){0.f,0.f,0.f,0.f};
            floatx4 s1 = (floatx4){0.f,0.f,0.f,0.f};
            const int R = mt * 16 + l16;
            #pragma unroll
            for (int kk = 0; kk < 2; ++kk) {
                bf16x8 kf = *(const bf16x8*)&Ksh[R * DH + (((kk * 4 + quad) ^ (l16 & 7)) * 8)];
                s0 = __builtin_amdgcn_mfma_f32_16x16x32_bf16(kf, qb[0][kk], s0, 0, 0, 0);
                s1 = __builtin_amdgcn_mfma_f32_16x16x32_bf16(kf, qb[1][kk], s1, 0, 0, 0);
            }
            if (domask) {
                #pragma unroll
                for (int r = 0; r < 4; ++r) {
                    const int keyg = k0 + mt * 16 + quad * 4 + r;
                    if (keyg > qw + l16)      s0[r] = -INFINITY;
                    if (keyg > qw + 16 + l16) s1[r] = -INFINITY;
                }
            }
            bf16x4 w0, w1;
            #pragma unroll
            for (int r = 0; r < 4; ++r) {
                const float p0 = __builtin_amdgcn_exp2f(CEXP * s0[r]);
                const float p1 = __builtin_amdgcn_exp2f(CEXP * s1[r]);
                lpart[0] += p0; lpart[1] += p1;
                w0[r] = (bf16)p0; w1[r] = (bf16)p1;
            }
            const int c0 = (mt * 2 + (quad >> 1)) ^ (l16 & 7);
            const int r1 = 16 + l16;
            const int c1 = (mt * 2 + (quad >> 1)) ^ (r1 & 7);
            *(bf16x4*)&Pw[l16 * TK + c0 * 8 + (quad & 1) * 4] = w0;
            *(bf16x4*)&Pw[r1  * TK + c1 * 8 + (quad & 1) * 4] = w1;
        }

        // ---- P^T B-fragments (wave-private, DS in-order) ----
        bf16x8 pf[2][2];
        #pragma unroll
        for (int nt = 0; nt < 2; ++nt) {
            const int row = nt * 16 + l16;
            #pragma unroll
            for (int kk = 0; kk < 2; ++kk)
                pf[nt][kk] = *(const bf16x8*)&Pw[row * TK + (((kk * 4 + quad) ^ (row & 7)) * 8)];
        }

        // ---- O^T += V^T · P^T ----
        #pragma unroll
        for (int kk = 0; kk < 2; ++kk) {
            #pragma unroll
            for (int mt = 0; mt < 4; ++mt) {
                const int R = mt * 16 + l16;
                bf16x8 vf = *(const bf16x8*)&Vsh[R * TK + (((kk * 4 + quad) ^ (l16 & 7)) * 8)];
                #pragma unroll
                for (int nt = 0; nt < 2; ++nt)
                    oacc[mt][nt] = __builtin_amdgcn_mfma_f32_16x16x32_bf16(vf, pf[nt][kk], oacc[mt][nt], 0, 0, 0);
            }
        }

        __syncthreads();   // group done reading K/V before next stage overwrites
    }

    // ---- cross-group combine through LDS (group 1 -> group 0) ----
    float* cb = (float*)smem + w4 * 2048;          // 8 KB per wave-pair
    float* lb = (float*)(smem + 16384) + w4 * 128; // lpart buffer
    if (g2 == 1) {
        #pragma unroll
        for (int mt = 0; mt < 4; ++mt)
            #pragma unroll
            for (int nt = 0; nt < 2; ++nt)
                *(floatx4*)&cb[((mt * 2 + nt) * 64 + lane) * 4] = oacc[mt][nt];
        lb[lane * 2 + 0] = lpart[0];
        lb[lane * 2 + 1] = lpart[1];
    }
    __syncthreads();
    if (g2 == 0) {
        lpart[0] += lb[lane * 2 + 0];
        lpart[1] += lb[lane * 2 + 1];
        float invl[2];
        #pragma unroll
        for (int nt = 0; nt < 2; ++nt) {
            float v = lpart[nt];
            v += __shfl_xor(v, 16);
            v += __shfl_xor(v, 32);
            invl[nt] = 1.0f / v;
        }
        #pragma unroll
        for (int nt = 0; nt < 2; ++nt) {
            const size_t qrow = (size_t)bh * T_SEQ + qw + nt * 16 + l16;
            #pragma unroll
            for (int mt = 0; mt < 4; ++mt) {
                floatx4 ob = *(const floatx4*)&cb[((mt * 2 + nt) * 64 + lane) * 4];
                float4 o;
                o.x = (oacc[mt][nt][0] + ob[0]) * invl[nt];
                o.y = (oacc[mt][nt][1] + ob[1]) * invl[nt];
                o.z = (oacc[mt][nt][2] + ob[2]) * invl[nt];
                o.w = (oacc[mt][nt][3] + ob[3]) * invl[nt];
                *(float4*)&Og[qrow * DH + mt * 16 + quad * 4] = o;
            }
        }
    }
}

extern "C" void kernel_launch(void* const* d_in, const int* in_sizes, int n_in,
                              void* d_out, int out_size, void* d_ws, size_t ws_size,
                              hipStream_t stream) {
    const float* Q = (const float*)d_in[0];
    const float* K = (const float*)d_in[1];
    const float* V = (const float*)d_in[2];
    float* O = (float*)d_out;
    (void)in_sizes; (void)n_in; (void)out_size; (void)ws_size;

    const size_t nelem = (size_t)BHN * T_SEQ * DH;   // 4,194,304
    bf16* Kbf = (bf16*)d_ws;            // 8 MiB
    bf16* Vtb = Kbf + nelem;            // 8 MiB

    prep<<<dim3(2048), dim3(256), 0, stream>>>(K, V, Kbf, Vtb);
    fa_fwd<<<dim3(512), dim3(512), 0, stream>>>(Q, Kbf, Vtb, O);
}